// Round 4
// baseline (791.077 us; speedup 1.0000x reference)
//
#include <hip/hip_runtime.h>
#include <hip/hip_bf16.h>
#include <cmath>

typedef __bf16 bf16;
typedef bf16 bf16x4 __attribute__((ext_vector_type(4)));
typedef float f32x4 __attribute__((ext_vector_type(4)));
typedef short short8 __attribute__((ext_vector_type(8)));
typedef short s16x4 __attribute__((ext_vector_type(4)));

#define S_LEN 4096
#define EMB   2048
#define NH    16
#define NKV   4
#define HD    128
#define WIN   2048

// ---------------------------------------------------------------------------
// Weight transpose+convert: W[K][N] f32 -> Wt[N][K] bf16. 32x32 LDS tiles.
// ---------------------------------------------------------------------------
__global__ __launch_bounds__(256)
void transpose_w(const float* __restrict__ W, bf16* __restrict__ Wt, int K, int N)
{
    __shared__ float t[32][33];
    const int k0 = blockIdx.x * 32, n0 = blockIdx.y * 32;
    const int tx = threadIdx.x & 31, ty = threadIdx.x >> 5;  // ty 0..7
    #pragma unroll
    for (int i = 0; i < 4; i++)
        t[ty + 8 * i][tx] = W[(long)(k0 + ty + 8 * i) * N + n0 + tx];
    __syncthreads();
    #pragma unroll
    for (int i = 0; i < 4; i++)
        Wt[(long)(n0 + ty + 8 * i) * K + k0 + tx] = (bf16)t[tx][ty + 8 * i];
}

// ---------------------------------------------------------------------------
// MFMA bf16 GEMM: C[M,N] = A[M,K] * Bt[N,K]^T, f32 accumulate.
// 128x128 tile, BK=32, 256 thr = 4 waves, each wave computes 64x64.
// (unchanged from round 3 — verified passing)
// ---------------------------------------------------------------------------
template<bool A_BF16, bool C_BF16>
__global__ __launch_bounds__(256)
void gemm_mfma(const void* __restrict__ Ap, const bf16* __restrict__ Bt,
               void* __restrict__ Cp, int M, int N, int K)
{
    __shared__ __align__(16) bf16 As[128 * 32];   // [m][k]
    __shared__ __align__(16) bf16 Bs[128 * 32];   // [n][k]
    char* AsB = (char*)As;
    char* BsB = (char*)Bs;
    const int tid = threadIdx.x;
    const int n0 = blockIdx.x * 128, m0 = blockIdx.y * 128;
    const int w = tid >> 6;
    const int wm = (w >> 1) * 64, wn = (w & 1) * 64;
    const int l16 = tid & 15, lq4 = (tid & 63) >> 4;

    const f32x4 fz = {0.f, 0.f, 0.f, 0.f};
    f32x4 acc[4][4];
    #pragma unroll
    for (int i = 0; i < 4; i++)
        #pragma unroll
        for (int j = 0; j < 4; j++) acc[i][j] = fz;

    const int sr = tid >> 1;
    const int sh = (tid & 1) * 16;
    const long arow = (long)(m0 + sr) * K;
    const long brow = (long)(n0 + sr) * K;
    const int wbase = sr * 64;
    const int swz = (sr & 7) << 4;

    for (int k0 = 0; k0 < K; k0 += 32) {
        __syncthreads();
        short8 av0, av1;
        if (A_BF16) {
            const bf16* A = (const bf16*)Ap;
            av0 = *(const short8*)(A + arow + k0 + sh);
            av1 = *(const short8*)(A + arow + k0 + sh + 8);
        } else {
            const float* A = (const float*)Ap;
            f32x4 a0 = *(const f32x4*)(A + arow + k0 + sh);
            f32x4 a1 = *(const f32x4*)(A + arow + k0 + sh + 4);
            f32x4 a2 = *(const f32x4*)(A + arow + k0 + sh + 8);
            f32x4 a3 = *(const f32x4*)(A + arow + k0 + sh + 12);
            bf16* p0 = (bf16*)&av0;
            bf16* p1 = (bf16*)&av1;
            #pragma unroll
            for (int i = 0; i < 4; i++) {
                p0[i]     = (bf16)a0[i];
                p0[4 + i] = (bf16)a1[i];
                p1[i]     = (bf16)a2[i];
                p1[4 + i] = (bf16)a3[i];
            }
        }
        short8 bv0 = *(const short8*)(Bt + brow + k0 + sh);
        short8 bv1 = *(const short8*)(Bt + brow + k0 + sh + 8);
        *(short8*)(AsB + ((wbase + sh * 2     ) ^ swz)) = av0;
        *(short8*)(AsB + ((wbase + sh * 2 + 16) ^ swz)) = av1;
        *(short8*)(BsB + ((wbase + sh * 2     ) ^ swz)) = bv0;
        *(short8*)(BsB + ((wbase + sh * 2 + 16) ^ swz)) = bv1;
        __syncthreads();

        short8 af[4], bfr[4];
        #pragma unroll
        for (int i = 0; i < 4; i++) {
            int mr = wm + i * 16 + l16;
            af[i]  = *(const short8*)(AsB + ((mr * 64 + lq4 * 16) ^ ((mr & 7) << 4)));
            int nr = wn + i * 16 + l16;
            bfr[i] = *(const short8*)(BsB + ((nr * 64 + lq4 * 16) ^ ((nr & 7) << 4)));
        }
        #pragma unroll
        for (int i = 0; i < 4; i++)
            #pragma unroll
            for (int j = 0; j < 4; j++)
                acc[i][j] = __builtin_amdgcn_mfma_f32_16x16x32_bf16(
                    af[i], bfr[j], acc[i][j], 0, 0, 0);
    }

    #pragma unroll
    for (int i = 0; i < 4; i++)
        #pragma unroll
        for (int r = 0; r < 4; r++) {
            long row = m0 + wm + i * 16 + lq4 * 4 + r;
            #pragma unroll
            for (int j = 0; j < 4; j++) {
                long col = n0 + wn + j * 16 + l16;
                if (C_BF16) ((bf16*)Cp)[row * N + col] = (bf16)acc[i][j][r];
                else        ((float*)Cp)[row * N + col] = acc[i][j][r];
            }
        }
}

// ---------------------------------------------------------------------------
// In-place RoPE on bf16 [S][nh*128] (f32 math). position_ids == arange(S).
// Used for K only; Q's RoPE is folded into attn_mfma's Q-load.
// ---------------------------------------------------------------------------
__global__ __launch_bounds__(256)
void rope_k(bf16* __restrict__ X, int nh)
{
    int idx = blockIdx.x * 256 + threadIdx.x;
    int i = idx & 63;
    int h = (idx >> 6) % nh;
    int s = idx / (64 * nh);
    bf16* p = X + (long)s * (nh * HD) + h * HD + i;
    float x1 = (float)p[0];
    float x2 = (float)p[64];
    float f = exp2f((float)i * (-13.287712379549449f / 64.0f)); // 10000^(-i/64)
    float ang = (float)s * f;
    float sn, cs;
    sincosf(ang, &sn, &cs);
    p[0]  = (bf16)(x1 * cs - x2 * sn);
    p[64] = (bf16)(x2 * cs + x1 * sn);
}

// ---------------------------------------------------------------------------
// Transpose V: Vb[S][NKV*HD] -> Vt[NKV*HD][S] (row index = kvh*128 + d).
// ---------------------------------------------------------------------------
__global__ __launch_bounds__(256)
void transpose_v(const bf16* __restrict__ V, bf16* __restrict__ Vt)
{
    __shared__ bf16 t[32][33];
    const int s0 = blockIdx.x * 32;
    const int d0 = blockIdx.y * 32;
    const int tx = threadIdx.x & 31, ty = threadIdx.x >> 5; // ty 0..7
    #pragma unroll
    for (int k = 0; k < 4; k++)
        t[ty + 8 * k][tx] = V[(long)(s0 + ty + 8 * k) * (NKV * HD) + d0 + tx];
    __syncthreads();
    #pragma unroll
    for (int k = 0; k < 4; k++) {
        int drow = d0 + ty + 8 * k;
        Vt[(long)drow * S_LEN + s0 + tx] = t[tx][ty + 8 * k];
    }
}

// ---------------------------------------------------------------------------
// MFMA flash attention v2 (sliding-window causal, GQA).
// Grid (S/64, NKV), 256 thr = 4 waves. Block = 64 q-rows x the WHOLE GQA
// group (4 q-heads share one K/V staging -> 4x less staging than v1).
// Wave w owns head kvh*4+w, all 64 q-rows (4 row-frags x 8 d-tiles accum).
// Async-STAGE split: next tile's K/V global loads issued into registers
// right after the post-stage barrier; ds_write next iteration (T14).
// RoPE(Q) applied in-register at Q-load (Qb is UN-roped).
// Per tile per wave: 64 QK MFMA + 64 PV MFMA between one barrier pair.
//   A-frag: row=lane&15, k=(lane>>4)*8+i ; B-frag: col=lane&15, same k
//   C: row=(lane>>4)*4+reg, col=lane&15   [verified m89]
// Pl padded to 76 (row stride 152B): P-writes bank-conflict-free
// (banks = 24*lq4 + {0..7} pattern covers all 32 banks 2x); P-reads 2x b64.
// ---------------------------------------------------------------------------
__global__ __launch_bounds__(256)
void attn_mfma(const bf16* __restrict__ Qb, const bf16* __restrict__ Kb,
               const bf16* __restrict__ Vt, bf16* __restrict__ Ob)
{
    __shared__ __align__(16) bf16 Kl[64 * 128];   // [key][d], byte^=((key&7)<<4)
    __shared__ __align__(16) bf16 Vl[128 * 64];   // [d][key], byte^=((d&7)<<4)
    __shared__ __align__(16) bf16 Pl[4][64][76];  // per-wave P, pad 76

    const int q0  = blockIdx.x * 64;
    const int kvh = blockIdx.y;
    const int tid = threadIdx.x;
    const int w   = tid >> 6;
    const int h   = kvh * 4 + w;
    const int l16 = tid & 15;
    const int lq4 = (tid & 63) >> 4;

    // ---- Q fragments with RoPE folded in (f32 math, bf16 in/out) ----
    short8 aQ[4][4];   // [row-frag i][k-chunk c]; rows q0+i*16+l16, d=c*32+lq4*8
    #pragma unroll
    for (int i = 0; i < 4; i++) {
        const int row = q0 + i * 16 + l16;
        const bf16* qp = Qb + (long)row * EMB + h * HD + lq4 * 8;
        float x[4][8];
        #pragma unroll
        for (int c = 0; c < 4; c++) {
            short8 v = *(const short8*)(qp + c * 32);
            #pragma unroll
            for (int ii = 0; ii < 8; ii++)
                x[c][ii] = (float)(((const bf16*)&v)[ii]);
        }
        #pragma unroll
        for (int c = 0; c < 2; c++)
            #pragma unroll
            for (int ii = 0; ii < 8; ii++) {
                int dm = c * 32 + lq4 * 8 + ii;            // d mod 64
                float f = exp2f((float)dm * (-13.287712379549449f / 64.0f));
                float sn, cs;
                sincosf((float)row * f, &sn, &cs);
                float x1 = x[c][ii], x2 = x[c + 2][ii];
                x[c][ii]     = x1 * cs - x2 * sn;
                x[c + 2][ii] = x2 * cs + x1 * sn;
            }
        #pragma unroll
        for (int c = 0; c < 4; c++) {
            short8 v;
            #pragma unroll
            for (int ii = 0; ii < 8; ii++)
                ((bf16*)&v)[ii] = (bf16)x[c][ii];
            aQ[i][c] = v;
        }
    }

    const f32x4 fz = {0.f, 0.f, 0.f, 0.f};
    float m[4][4], lsum[4][4];
    f32x4 accO[4][8];
    #pragma unroll
    for (int i = 0; i < 4; i++)
        #pragma unroll
        for (int r = 0; r < 4; r++) { m[i][r] = -1e30f; lsum[i][r] = 0.f; }
    #pragma unroll
    for (int i = 0; i < 4; i++)
        #pragma unroll
        for (int dt = 0; dt < 8; dt++) accO[i][dt] = fz;

    const int jb0 = (q0 >= WIN) ? q0 - WIN : 0;
    char* KlB = (char*)Kl;
    char* VlB = (char*)Vl;

    // prologue: issue first tile's loads into registers
    short8 stgK[4], stgV[4];
    #pragma unroll
    for (int it = 0; it < 4; it++) {
        int c = it * 256 + tid;
        stgK[it] = *(const short8*)(Kb + (long)(jb0 + (c >> 4)) * (NKV * HD) + kvh * HD + (c & 15) * 8);
        stgV[it] = *(const short8*)(Vt + ((long)kvh * HD + (c >> 3)) * S_LEN + jb0 + (c & 7) * 8);
    }

    for (int jb = jb0; jb <= q0; jb += 64) {
        __syncthreads();   // previous tile's LDS readers done
        #pragma unroll
        for (int it = 0; it < 4; it++) {
            int c = it * 256 + tid;
            int key = c >> 4, d0 = (c & 15) * 8;
            *(short8*)(KlB + ((key * 256 + d0 * 2) ^ ((key & 7) << 4))) = stgK[it];
            int d = c >> 3, k0 = (c & 7) * 8;
            *(short8*)(VlB + ((d * 128 + k0 * 2) ^ ((d & 7) << 4))) = stgV[it];
        }
        __syncthreads();
        // async prefetch next tile (hidden under this tile's compute)
        if (jb + 64 <= q0) {
            #pragma unroll
            for (int it = 0; it < 4; it++) {
                int c = it * 256 + tid;
                stgK[it] = *(const short8*)(Kb + (long)(jb + 64 + (c >> 4)) * (NKV * HD) + kvh * HD + (c & 15) * 8);
                stgV[it] = *(const short8*)(Vt + ((long)kvh * HD + (c >> 3)) * S_LEN + jb + 64 + (c & 7) * 8);
            }
        }

        // --- QK^T: 64 q-rows x 64 keys (4 row-frags x 4 col-frags x 4 k) ---
        f32x4 s[4][4];
        #pragma unroll
        for (int jt = 0; jt < 4; jt++) {
            const int key = jt * 16 + l16;
            short8 bk[4];
            #pragma unroll
            for (int c = 0; c < 4; c++)
                bk[c] = *(const short8*)(
                    KlB + ((key * 256 + c * 64 + lq4 * 16) ^ ((key & 7) << 4)));
            #pragma unroll
            for (int i = 0; i < 4; i++) {
                f32x4 a = fz;
                #pragma unroll
                for (int c = 0; c < 4; c++)
                    a = __builtin_amdgcn_mfma_f32_16x16x32_bf16(aQ[i][c], bk[c], a, 0, 0, 0);
                s[i][jt] = a;
            }
        }

        // --- scale (+mask only on first/last tile) + row max over l16 ---
        float tmax[4][4];
        #pragma unroll
        for (int i = 0; i < 4; i++)
            #pragma unroll
            for (int r = 0; r < 4; r++) tmax[i][r] = -1e30f;
        const bool need_mask = (jb == q0) || (q0 >= WIN && jb == jb0);
        if (need_mask) {
            #pragma unroll
            for (int jt = 0; jt < 4; jt++) {
                const int j = jb + jt * 16 + l16;
                #pragma unroll
                for (int i = 0; i < 4; i++)
                    #pragma unroll
                    for (int r = 0; r < 4; r++) {
                        const int qi = q0 + i * 16 + lq4 * 4 + r;
                        float sv = s[i][jt][r] * 0.08838834764831845f;
                        if (j > qi || j < qi - WIN) sv = -1e30f;
                        s[i][jt][r] = sv;
                        tmax[i][r] = fmaxf(tmax[i][r], sv);
                    }
            }
        } else {
            #pragma unroll
            for (int jt = 0; jt < 4; jt++)
                #pragma unroll
                for (int i = 0; i < 4; i++)
                    #pragma unroll
                    for (int r = 0; r < 4; r++) {
                        float sv = s[i][jt][r] * 0.08838834764831845f;
                        s[i][jt][r] = sv;
                        tmax[i][r] = fmaxf(tmax[i][r], sv);
                    }
        }
        #pragma unroll
        for (int i = 0; i < 4; i++)
            #pragma unroll
            for (int r = 0; r < 4; r++) {
                float t = tmax[i][r];
                t = fmaxf(t, __shfl_xor(t, 1, 64));
                t = fmaxf(t, __shfl_xor(t, 2, 64));
                t = fmaxf(t, __shfl_xor(t, 4, 64));
                t = fmaxf(t, __shfl_xor(t, 8, 64));
                tmax[i][r] = t;
            }

        // --- online softmax update ---
        float alpha[4][4];
        #pragma unroll
        for (int i = 0; i < 4; i++)
            #pragma unroll
            for (int r = 0; r < 4; r++) {
                float mn = fmaxf(m[i][r], tmax[i][r]);
                alpha[i][r] = __expf(m[i][r] - mn);
                m[i][r] = mn;
            }
        float rsum[4][4];
        #pragma unroll
        for (int i = 0; i < 4; i++)
            #pragma unroll
            for (int r = 0; r < 4; r++) rsum[i][r] = 0.f;
        #pragma unroll
        for (int i = 0; i < 4; i++)
            #pragma unroll
            for (int jt = 0; jt < 4; jt++)
                #pragma unroll
                for (int r = 0; r < 4; r++) {
                    float pv = __expf(s[i][jt][r] - m[i][r]);  // masked -> 0
                    bf16 pb = (bf16)pv;
                    Pl[w][i * 16 + lq4 * 4 + r][jt * 16 + l16] = pb;
                    rsum[i][r] += (float)pb;   // denom from ROUNDED p
                }
        #pragma unroll
        for (int i = 0; i < 4; i++)
            #pragma unroll
            for (int r = 0; r < 4; r++) {
                float t = rsum[i][r];
                t += __shfl_xor(t, 1, 64);
                t += __shfl_xor(t, 2, 64);
                t += __shfl_xor(t, 4, 64);
                t += __shfl_xor(t, 8, 64);
                lsum[i][r] = lsum[i][r] * alpha[i][r] + t;
            }
        #pragma unroll
        for (int i = 0; i < 4; i++)
            #pragma unroll
            for (int dt = 0; dt < 8; dt++)
                #pragma unroll
                for (int r = 0; r < 4; r++)
                    accO[i][dt][r] *= alpha[i][r];

        // --- PV: O[64x128] += P[64x64] * V[64x128] ---
        // (P write->read same wave: DS ops complete in issue order per wave)
        #pragma unroll
        for (int kc = 0; kc < 2; kc++) {
            short8 ap[4];
            #pragma unroll
            for (int i = 0; i < 4; i++) {
                const char* pp = (const char*)&Pl[w][i * 16 + l16][kc * 32 + lq4 * 8];
                s16x4 lo = *(const s16x4*)pp;
                s16x4 hi = *(const s16x4*)(pp + 8);
                short8 a;
                #pragma unroll
                for (int k = 0; k < 4; k++) { a[k] = lo[k]; a[4 + k] = hi[k]; }
                ap[i] = a;
            }
            #pragma unroll
            for (int dt = 0; dt < 8; dt++) {
                int d = dt * 16 + l16;
                short8 bv = *(const short8*)(
                    VlB + ((d * 128 + kc * 64 + lq4 * 16) ^ ((d & 7) << 4)));
                #pragma unroll
                for (int i = 0; i < 4; i++)
                    accO[i][dt] = __builtin_amdgcn_mfma_f32_16x16x32_bf16(
                        ap[i], bv, accO[i][dt], 0, 0, 0);
            }
        }
    }

    // --- epilogue: normalize and store ---
    #pragma unroll
    for (int i = 0; i < 4; i++)
        #pragma unroll
        for (int r = 0; r < 4; r++) {
            float inv = 1.0f / lsum[i][r];
            int qi = q0 + i * 16 + lq4 * 4 + r;
            bf16* op = Ob + (long)qi * EMB + h * HD + l16;
            #pragma unroll
            for (int dt = 0; dt < 8; dt++)
                op[dt * 16] = (bf16)(accO[i][dt][r] * inv);
        }
}

// ---------------------------------------------------------------------------
extern "C" void kernel_launch(void* const* d_in, const int* in_sizes, int n_in,
                              void* d_out, int out_size, void* d_ws, size_t ws_size,
                              hipStream_t stream)
{
    (void)out_size; (void)ws_size;
    int idx_pos = -1;
    for (int i = 0; i < n_in; i++)
        if (in_sizes[i] == 4096) { idx_pos = i; break; }
    int bigs[3] = {0, 1, 2}, w4[2] = {4, 6}, w1[2] = {5, 5};
    int nb = 0, n4 = 0, n1 = 0;
    for (int i = 0; i < n_in; i++) {
        if (in_sizes[i] == 8388608 && nb < 3) bigs[nb++] = i;
        else if (in_sizes[i] == 4194304 && n4 < 2) w4[n4++] = i;
        else if (in_sizes[i] == 1048576 && n1 < 2) w1[n1++] = i;
    }
    bool alpha = (idx_pos == 1);
    int iq  = alpha ? bigs[1] : bigs[0];
    int ik  = alpha ? bigs[0] : bigs[1];
    int iv  = bigs[2];
    int iwq = alpha ? w4[1] : w4[0];
    int iwo = alpha ? w4[0] : w4[1];
    int iwk = w1[0];
    int iwv = w1[1];
    const float* query = (const float*)d_in[iq];
    const float* key   = (const float*)d_in[ik];
    const float* value = (const float*)d_in[iv];
    const float* wq = (const float*)d_in[iwq];
    const float* wk = (const float*)d_in[iwk];
    const float* wv = (const float*)d_in[iwv];
    const float* wo = (const float*)d_in[iwo];

    // Workspace lifetimes (peak 28 MiB):
    //   Kb [0,4M)  Vb [4,8M)  Ob [8,24M)  Vt [24,28M)
    //   wqT [8,16M) (dead before Ob);  wkT [24,26M), wvT [26,28M) (dead before Vt)
    //   woT [0,8M)  (written after Kb/Vb dead)
    bf16* Qb = (bf16*)d_out;                 // d_out[0:16M), dead before final GEMM
    char* ws = (char*)d_ws;
    bf16* Kb  = (bf16*)(ws);
    bf16* Vb  = (bf16*)(ws + (4u  << 20));
    bf16* Ob  = (bf16*)(ws + (8u  << 20));
    bf16* wqT = (bf16*)(ws + (8u  << 20));
    bf16* Vt  = (bf16*)(ws + (24u << 20));
    bf16* wkT = (bf16*)(ws + (24u << 20));
    bf16* wvT = (bf16*)(ws + (26u << 20));
    bf16* woT = (bf16*)(ws);

    dim3 blk(256);
    transpose_w<<<dim3(EMB / 32, EMB / 32), blk, 0, stream>>>(wq, wqT, EMB, EMB);
    transpose_w<<<dim3(EMB / 32, (NKV * HD) / 32), blk, 0, stream>>>(wk, wkT, EMB, NKV * HD);
    transpose_w<<<dim3(EMB / 32, (NKV * HD) / 32), blk, 0, stream>>>(wv, wvT, EMB, NKV * HD);

    gemm_mfma<false, true><<<dim3(EMB / 128, S_LEN / 128), blk, 0, stream>>>(
        query, wqT, Qb, S_LEN, EMB, EMB);
    gemm_mfma<false, true><<<dim3((NKV * HD) / 128, S_LEN / 128), blk, 0, stream>>>(
        key, wkT, Kb, S_LEN, NKV * HD, EMB);
    gemm_mfma<false, true><<<dim3((NKV * HD) / 128, S_LEN / 128), blk, 0, stream>>>(
        value, wvT, Vb, S_LEN, NKV * HD, EMB);

    rope_k<<<(S_LEN * NKV * 64) / 256, blk, 0, stream>>>(Kb, NKV);   // K only
    transpose_v<<<dim3(S_LEN / 32, (NKV * HD) / 32), blk, 0, stream>>>(Vb, Vt);
    attn_mfma<<<dim3(S_LEN / 64, NKV), blk, 0, stream>>>(Qb, Kb, Vt, Ob);

    transpose_w<<<dim3((NH * HD) / 32, EMB / 32), blk, 0, stream>>>(wo, woT, NH * HD, EMB);
    gemm_mfma<true, false><<<dim3(EMB / 128, S_LEN / 128), blk, 0, stream>>>(
        Ob, woT, d_out, S_LEN, EMB, EMB);
}

// Round 5
// 616.998 us; speedup vs baseline: 1.2821x; 1.2821x over previous
//
#include <hip/hip_runtime.h>
#include <hip/hip_bf16.h>
#include <cmath>

typedef __bf16 bf16;
typedef bf16 bf16x4 __attribute__((ext_vector_type(4)));
typedef float f32x4 __attribute__((ext_vector_type(4)));
typedef short short8 __attribute__((ext_vector_type(8)));

#define S_LEN 4096
#define EMB   2048
#define NH    16
#define NKV   4
#define HD    128
#define WIN   2048

// ---------------------------------------------------------------------------
// f32 -> bf16 streaming convert (8 elems/thread).
// ---------------------------------------------------------------------------
__global__ __launch_bounds__(256)
void cvt_f32_bf16(const float* __restrict__ X, bf16* __restrict__ Y)
{
    long i = ((long)blockIdx.x * 256 + threadIdx.x) * 8;
    f32x4 a = *(const f32x4*)(X + i);
    f32x4 b = *(const f32x4*)(X + i + 4);
    short8 v;
    #pragma unroll
    for (int k = 0; k < 4; k++) {
        ((bf16*)&v)[k]     = (bf16)a[k];
        ((bf16*)&v)[4 + k] = (bf16)b[k];
    }
    *(short8*)(Y + i) = v;
}

// ---------------------------------------------------------------------------
// Weight transpose+convert: W[K][N] f32 -> Wt[N][K] bf16. 32x32 LDS tiles.
// ---------------------------------------------------------------------------
__global__ __launch_bounds__(256)
void transpose_w(const float* __restrict__ W, bf16* __restrict__ Wt, int K, int N)
{
    __shared__ float t[32][33];
    const int k0 = blockIdx.x * 32, n0 = blockIdx.y * 32;
    const int tx = threadIdx.x & 31, ty = threadIdx.x >> 5;  // ty 0..7
    #pragma unroll
    for (int i = 0; i < 4; i++)
        t[ty + 8 * i][tx] = W[(long)(k0 + ty + 8 * i) * N + n0 + tx];
    __syncthreads();
    #pragma unroll
    for (int i = 0; i < 4; i++)
        Wt[(long)(n0 + ty + 8 * i) * K + k0 + tx] = (bf16)t[tx][ty + 8 * i];
}

// ---------------------------------------------------------------------------
// MFMA bf16 GEMM: C[M,N] = A[M,K] * Bt[N,K]^T, f32 accumulate.
// 128x128 tile, BK=32, 256 thr = 4 waves, each wave computes 64x64.
// (unchanged from round 3 — verified passing)
// ---------------------------------------------------------------------------
template<bool A_BF16, bool C_BF16>
__global__ __launch_bounds__(256)
void gemm_mfma(const void* __restrict__ Ap, const bf16* __restrict__ Bt,
               void* __restrict__ Cp, int M, int N, int K)
{
    __shared__ __align__(16) bf16 As[128 * 32];   // [m][k]
    __shared__ __align__(16) bf16 Bs[128 * 32];   // [n][k]
    char* AsB = (char*)As;
    char* BsB = (char*)Bs;
    const int tid = threadIdx.x;
    const int n0 = blockIdx.x * 128, m0 = blockIdx.y * 128;
    const int w = tid >> 6;
    const int wm = (w >> 1) * 64, wn = (w & 1) * 64;
    const int l16 = tid & 15, lq4 = (tid & 63) >> 4;

    const f32x4 fz = {0.f, 0.f, 0.f, 0.f};
    f32x4 acc[4][4];
    #pragma unroll
    for (int i = 0; i < 4; i++)
        #pragma unroll
        for (int j = 0; j < 4; j++) acc[i][j] = fz;

    const int sr = tid >> 1;
    const int sh = (tid & 1) * 16;
    const long arow = (long)(m0 + sr) * K;
    const long brow = (long)(n0 + sr) * K;
    const int wbase = sr * 64;
    const int swz = (sr & 7) << 4;

    for (int k0 = 0; k0 < K; k0 += 32) {
        __syncthreads();
        short8 av0, av1;
        if (A_BF16) {
            const bf16* A = (const bf16*)Ap;
            av0 = *(const short8*)(A + arow + k0 + sh);
            av1 = *(const short8*)(A + arow + k0 + sh + 8);
        } else {
            const float* A = (const float*)Ap;
            f32x4 a0 = *(const f32x4*)(A + arow + k0 + sh);
            f32x4 a1 = *(const f32x4*)(A + arow + k0 + sh + 4);
            f32x4 a2 = *(const f32x4*)(A + arow + k0 + sh + 8);
            f32x4 a3 = *(const f32x4*)(A + arow + k0 + sh + 12);
            bf16* p0 = (bf16*)&av0;
            bf16* p1 = (bf16*)&av1;
            #pragma unroll
            for (int i = 0; i < 4; i++) {
                p0[i]     = (bf16)a0[i];
                p0[4 + i] = (bf16)a1[i];
                p1[i]     = (bf16)a2[i];
                p1[4 + i] = (bf16)a3[i];
            }
        }
        short8 bv0 = *(const short8*)(Bt + brow + k0 + sh);
        short8 bv1 = *(const short8*)(Bt + brow + k0 + sh + 8);
        *(short8*)(AsB + ((wbase + sh * 2     ) ^ swz)) = av0;
        *(short8*)(AsB + ((wbase + sh * 2 + 16) ^ swz)) = av1;
        *(short8*)(BsB + ((wbase + sh * 2     ) ^ swz)) = bv0;
        *(short8*)(BsB + ((wbase + sh * 2 + 16) ^ swz)) = bv1;
        __syncthreads();

        short8 af[4], bfr[4];
        #pragma unroll
        for (int i = 0; i < 4; i++) {
            int mr = wm + i * 16 + l16;
            af[i]  = *(const short8*)(AsB + ((mr * 64 + lq4 * 16) ^ ((mr & 7) << 4)));
            int nr = wn + i * 16 + l16;
            bfr[i] = *(const short8*)(BsB + ((nr * 64 + lq4 * 16) ^ ((nr & 7) << 4)));
        }
        #pragma unroll
        for (int i = 0; i < 4; i++)
            #pragma unroll
            for (int j = 0; j < 4; j++)
                acc[i][j] = __builtin_amdgcn_mfma_f32_16x16x32_bf16(
                    af[i], bfr[j], acc[i][j], 0, 0, 0);
    }

    #pragma unroll
    for (int i = 0; i < 4; i++)
        #pragma unroll
        for (int r = 0; r < 4; r++) {
            long row = m0 + wm + i * 16 + lq4 * 4 + r;
            #pragma unroll
            for (int j = 0; j < 4; j++) {
                long col = n0 + wn + j * 16 + l16;
                if (C_BF16) ((bf16*)Cp)[row * N + col] = (bf16)acc[i][j][r];
                else        ((float*)Cp)[row * N + col] = acc[i][j][r];
            }
        }
}

// ---------------------------------------------------------------------------
// In-place RoPE on bf16 [S][nh*128] (f32 math). position_ids == arange(S).
// ---------------------------------------------------------------------------
__global__ __launch_bounds__(256)
void rope_k(bf16* __restrict__ X, int nh)
{
    int idx = blockIdx.x * 256 + threadIdx.x;
    int i = idx & 63;
    int h = (idx >> 6) % nh;
    int s = idx / (64 * nh);
    bf16* p = X + (long)s * (nh * HD) + h * HD + i;
    float x1 = (float)p[0];
    float x2 = (float)p[64];
    float f = exp2f((float)i * (-13.287712379549449f / 64.0f)); // 10000^(-i/64)
    float ang = (float)s * f;
    float sn, cs;
    sincosf(ang, &sn, &cs);
    p[0]  = (bf16)(x1 * cs - x2 * sn);
    p[64] = (bf16)(x2 * cs + x1 * sn);
}

// ---------------------------------------------------------------------------
// Transpose V: Vb[S][NKV*HD] -> Vt[NKV*HD][S] (row index = kvh*128 + d).
// ---------------------------------------------------------------------------
__global__ __launch_bounds__(256)
void transpose_v(const bf16* __restrict__ V, bf16* __restrict__ Vt)
{
    __shared__ bf16 t[32][33];
    const int s0 = blockIdx.x * 32;
    const int d0 = blockIdx.y * 32;
    const int tx = threadIdx.x & 31, ty = threadIdx.x >> 5; // ty 0..7
    #pragma unroll
    for (int k = 0; k < 4; k++)
        t[ty + 8 * k][tx] = V[(long)(s0 + ty + 8 * k) * (NKV * HD) + d0 + tx];
    __syncthreads();
    #pragma unroll
    for (int k = 0; k < 4; k++) {
        int drow = d0 + ty + 8 * k;
        Vt[(long)drow * S_LEN + s0 + tx] = t[tx][ty + 8 * k];
    }
}

// ---------------------------------------------------------------------------
// MFMA flash attention v3 (sliding-window causal, GQA).
// v1 structure (grid (S/64,NH), 4 waves, wave = 16 q-rows x 1 head; 132 VGPR
// proven) + swapped-operand softmax:
//   QK^T computed as mfma(K, Q) -> C = S^T: lane holds S[key=jt*16+lq4*4+r]
//   [q = qw+l16]. Row-softmax is 15 in-lane ops + 2 shuffles (xor16/32)
//   instead of 32 serial shuffles/tile; m/lsum are per-lane SCALARS.
//   PV computed as mfma(V^T, P^T) -> C = O^T: accO[dt][r] =
//   O[qw+l16][dt*16+lq4*4+r]; alpha/lsum stay lane-local, epilogue = 8B stores.
// Extras: T14 prefetch (stgK/stgV regs, ~+32 VGPR, total ~145 < 170 =
// 3 waves/SIMD); mask math only on first/last tile (only tiles that can
// contain masked keys: causal -> jb==q0, window -> jb==jb0 when q0>=WIN);
// LPT ordering (qb reversed: 33-tile blocks dispatch first).
// ---------------------------------------------------------------------------
__global__ __launch_bounds__(256)
void attn_mfma(const bf16* __restrict__ Qb, const bf16* __restrict__ Kb,
               const bf16* __restrict__ Vt, bf16* __restrict__ Ob)
{
    __shared__ __align__(16) bf16 Kl[64 * 128];   // [key][d], byte^=((key&7)<<4)
    __shared__ __align__(16) bf16 Vl[128 * 64];   // [d][key], byte^=((d&7)<<4)
    __shared__ __align__(16) bf16 Pl[4][16][72];  // per-wave P[q][key], pad 72

    const int qb  = (int)gridDim.x - 1 - blockIdx.x;   // LPT: long blocks first
    const int q0  = qb * 64;
    const int h   = blockIdx.y;
    const int kvh = h >> 2;
    const int tid = threadIdx.x;
    const int w   = tid >> 6;
    const int l16 = tid & 15;
    const int lq4 = (tid & 63) >> 4;
    const int qw  = q0 + w * 16;
    const int qi  = qw + l16;            // this lane's softmax q-row

    // Q as B-frag: lane holds Q[qi][c*32 + lq4*8 .. +8]
    short8 aQ[4];
    {
        const bf16* qp = Qb + (long)qi * EMB + h * HD + lq4 * 8;
        #pragma unroll
        for (int c = 0; c < 4; c++) aQ[c] = *(const short8*)(qp + c * 32);
    }

    const f32x4 fz = {0.f, 0.f, 0.f, 0.f};
    float mrow = -1e30f, lrow = 0.f;
    f32x4 accO[8];   // accO[dt][r] = O[qi][dt*16 + lq4*4 + r]
    #pragma unroll
    for (int dt = 0; dt < 8; dt++) accO[dt] = fz;

    const int jb0 = (q0 >= WIN) ? q0 - WIN : 0;
    char* KlB = (char*)Kl;
    char* VlB = (char*)Vl;

    // T14 prologue: first tile's loads into registers
    short8 stgK[4], stgV[4];
    #pragma unroll
    for (int it = 0; it < 4; it++) {
        int c = it * 256 + tid;
        stgK[it] = *(const short8*)(Kb + (long)(jb0 + (c >> 4)) * (NKV * HD) + kvh * HD + (c & 15) * 8);
        stgV[it] = *(const short8*)(Vt + ((long)kvh * HD + (c >> 3)) * S_LEN + jb0 + (c & 7) * 8);
    }

    for (int jb = jb0; jb <= q0; jb += 64) {
        __syncthreads();   // previous tile's LDS readers done
        #pragma unroll
        for (int it = 0; it < 4; it++) {
            int c = it * 256 + tid;
            int key = c >> 4, d0 = (c & 15) * 8;
            *(short8*)(KlB + ((key * 256 + d0 * 2) ^ ((key & 7) << 4))) = stgK[it];
            int d = c >> 3, k0 = (c & 7) * 8;
            *(short8*)(VlB + ((d * 128 + k0 * 2) ^ ((d & 7) << 4))) = stgV[it];
        }
        __syncthreads();
        // prefetch next tile (in flight under this tile's compute)
        if (jb + 64 <= q0) {
            #pragma unroll
            for (int it = 0; it < 4; it++) {
                int c = it * 256 + tid;
                stgK[it] = *(const short8*)(Kb + (long)(jb + 64 + (c >> 4)) * (NKV * HD) + kvh * HD + (c & 15) * 8);
                stgV[it] = *(const short8*)(Vt + ((long)kvh * HD + (c >> 3)) * S_LEN + jb + 64 + (c & 7) * 8);
            }
        }

        // --- QK^T swapped: s[jt][r] = S[key = jb+jt*16+lq4*4+r][qi] ---
        f32x4 s[4];
        #pragma unroll
        for (int jt = 0; jt < 4; jt++) {
            const int key = jt * 16 + l16;
            f32x4 a = fz;
            #pragma unroll
            for (int c = 0; c < 4; c++) {
                short8 bk = *(const short8*)(
                    KlB + ((key * 256 + c * 64 + lq4 * 16) ^ ((key & 7) << 4)));
                a = __builtin_amdgcn_mfma_f32_16x16x32_bf16(bk, aQ[c], a, 0, 0, 0);
            }
            s[jt] = a;
        }

        // --- scale (+mask only first/last tile) + per-lane row max ---
        float tmax = -1e30f;
        const bool need_mask = (jb == q0) || (q0 >= WIN && jb == jb0);
        if (need_mask) {
            #pragma unroll
            for (int jt = 0; jt < 4; jt++)
                #pragma unroll
                for (int r = 0; r < 4; r++) {
                    int j = jb + jt * 16 + lq4 * 4 + r;
                    float sv = s[jt][r] * 0.08838834764831845f;  // 1/sqrt(128)
                    if (j > qi || j < qi - WIN) sv = -1e30f;
                    s[jt][r] = sv;
                    tmax = fmaxf(tmax, sv);
                }
        } else {
            #pragma unroll
            for (int jt = 0; jt < 4; jt++)
                #pragma unroll
                for (int r = 0; r < 4; r++) {
                    float sv = s[jt][r] * 0.08838834764831845f;
                    s[jt][r] = sv;
                    tmax = fmaxf(tmax, sv);
                }
        }
        tmax = fmaxf(tmax, __shfl_xor(tmax, 16, 64));
        tmax = fmaxf(tmax, __shfl_xor(tmax, 32, 64));

        // --- online softmax update (scalars; lane owns row qi) ---
        float mn = fmaxf(mrow, tmax);
        float alpha = __expf(mrow - mn);   // first tile: exp(-huge)=0
        mrow = mn;
        float rsum = 0.f;
        #pragma unroll
        for (int jt = 0; jt < 4; jt++) {
            bf16x4 pb4;
            #pragma unroll
            for (int r = 0; r < 4; r++) {
                float pv = __expf(s[jt][r] - mn);   // masked -> 0
                bf16 pb = (bf16)pv;
                pb4[r] = pb;
                rsum += (float)pb;   // denom from ROUNDED p (consistency)
            }
            *(bf16x4*)&Pl[w][l16][jt * 16 + lq4 * 4] = pb4;   // 8B write
        }
        rsum += __shfl_xor(rsum, 16, 64);
        rsum += __shfl_xor(rsum, 32, 64);
        lrow = lrow * alpha + rsum;
        #pragma unroll
        for (int dt = 0; dt < 8; dt++)
            accO[dt] *= alpha;

        // --- PV swapped: O^T = V^T * P^T ; accO[dt] row=d-sub col=q ---
        #pragma unroll
        for (int kc = 0; kc < 2; kc++) {
            short8 ap = *(const short8*)&Pl[w][l16][kc * 32 + lq4 * 8];
            #pragma unroll
            for (int dt = 0; dt < 8; dt++) {
                int d = dt * 16 + l16;
                short8 bv = *(const short8*)(
                    VlB + ((d * 128 + kc * 64 + lq4 * 16) ^ ((d & 7) << 4)));
                accO[dt] = __builtin_amdgcn_mfma_f32_16x16x32_bf16(bv, ap, accO[dt], 0, 0, 0);
            }
        }
    }

    // --- epilogue: normalize, pack 4 bf16, one 8B store per dt ---
    float inv = 1.0f / lrow;
    bf16* op = Ob + (long)qi * EMB + h * HD + lq4 * 4;
    #pragma unroll
    for (int dt = 0; dt < 8; dt++) {
        bf16x4 o4;
        #pragma unroll
        for (int r = 0; r < 4; r++) o4[r] = (bf16)(accO[dt][r] * inv);
        *(bf16x4*)(op + dt * 16) = o4;
    }
}

// ---------------------------------------------------------------------------
extern "C" void kernel_launch(void* const* d_in, const int* in_sizes, int n_in,
                              void* d_out, int out_size, void* d_ws, size_t ws_size,
                              hipStream_t stream)
{
    (void)out_size; (void)ws_size;
    int idx_pos = -1;
    for (int i = 0; i < n_in; i++)
        if (in_sizes[i] == 4096) { idx_pos = i; break; }
    int bigs[3] = {0, 1, 2}, w4[2] = {4, 6}, w1[2] = {5, 5};
    int nb = 0, n4 = 0, n1 = 0;
    for (int i = 0; i < n_in; i++) {
        if (in_sizes[i] == 8388608 && nb < 3) bigs[nb++] = i;
        else if (in_sizes[i] == 4194304 && n4 < 2) w4[n4++] = i;
        else if (in_sizes[i] == 1048576 && n1 < 2) w1[n1++] = i;
    }
    bool alpha = (idx_pos == 1);
    int iq  = alpha ? bigs[1] : bigs[0];
    int ik  = alpha ? bigs[0] : bigs[1];
    int iv  = bigs[2];
    int iwq = alpha ? w4[1] : w4[0];
    int iwo = alpha ? w4[0] : w4[1];
    int iwk = w1[0];
    int iwv = w1[1];
    const float* query = (const float*)d_in[iq];
    const float* key   = (const float*)d_in[ik];
    const float* value = (const float*)d_in[iv];
    const float* wq = (const float*)d_in[iwq];
    const float* wk = (const float*)d_in[iwk];
    const float* wv = (const float*)d_in[iwv];
    const float* wo = (const float*)d_in[iwo];

    // Workspace lifetimes (peak 28 MiB, stream-ordered):
    //   phase 1: wqT [0,8M) ; Qf [8,24M)         (gemm-Q reads both)
    //   phase 2: Kb [0,4M), Vb [4,8M)            (overwrite dead wqT)
    //            wkT [24,26M), wvT [26,28M)      (dead before Vt)
    //   phase 3: Vt [24,28M)                     (after wkT/wvT dead)
    //            Ob [8,24M)                      (overwrites dead Qf)
    //   phase 4: woT [0,8M)                      (after attn: Kb/Vb dead)
    bf16* Qb  = (bf16*)d_out;                // d_out[0:16M), dead before final GEMM
    char* ws = (char*)d_ws;
    bf16* wqT = (bf16*)(ws);
    bf16* Qf  = (bf16*)(ws + (8u  << 20));
    bf16* Kb  = (bf16*)(ws);
    bf16* Vb  = (bf16*)(ws + (4u  << 20));
    bf16* Ob  = (bf16*)(ws + (8u  << 20));
    bf16* Vt  = (bf16*)(ws + (24u << 20));
    bf16* wkT = (bf16*)(ws + (24u << 20));
    bf16* wvT = (bf16*)(ws + (26u << 20));
    bf16* woT = (bf16*)(ws);

    dim3 blk(256);
    // phase 1: Q projection (bf16 A halves its re-fetch traffic)
    transpose_w<<<dim3(EMB / 32, EMB / 32), blk, 0, stream>>>(wq, wqT, EMB, EMB);
    cvt_f32_bf16<<<(S_LEN * EMB) / 2048, blk, 0, stream>>>(query, Qf);
    gemm_mfma<true, true><<<dim3(EMB / 128, S_LEN / 128), blk, 0, stream>>>(
        Qf, wqT, Qb, S_LEN, EMB, EMB);

    // phase 2: K/V projections
    transpose_w<<<dim3(EMB / 32, (NKV * HD) / 32), blk, 0, stream>>>(wk, wkT, EMB, NKV * HD);
    transpose_w<<<dim3(EMB / 32, (NKV * HD) / 32), blk, 0, stream>>>(wv, wvT, EMB, NKV * HD);
    gemm_mfma<false, true><<<dim3((NKV * HD) / 128, S_LEN / 128), blk, 0, stream>>>(
        key, wkT, Kb, S_LEN, NKV * HD, EMB);
    gemm_mfma<false, true><<<dim3((NKV * HD) / 128, S_LEN / 128), blk, 0, stream>>>(
        value, wvT, Vb, S_LEN, NKV * HD, EMB);

    // phase 3: RoPE + attention
    rope_k<<<(S_LEN * NH * 64) / 256, blk, 0, stream>>>(Qb, NH);
    rope_k<<<(S_LEN * NKV * 64) / 256, blk, 0, stream>>>(Kb, NKV);
    transpose_v<<<dim3(S_LEN / 32, (NKV * HD) / 32), blk, 0, stream>>>(Vb, Vt);
    attn_mfma<<<dim3(S_LEN / 64, NH), blk, 0, stream>>>(Qb, Kb, Vt, Ob);

    // phase 4: output projection
    transpose_w<<<dim3((NH * HD) / 32, EMB / 32), blk, 0, stream>>>(wo, woT, NH * HD, EMB);
    gemm_mfma<true, false><<<dim3(EMB / 128, S_LEN / 128), blk, 0, stream>>>(
        Ob, woT, d_out, S_LEN, EMB, EMB);
}

// Round 6
// 613.693 us; speedup vs baseline: 1.2890x; 1.0054x over previous
//
#include <hip/hip_runtime.h>
#include <hip/hip_bf16.h>
#include <cmath>

typedef __bf16 bf16;
typedef bf16 bf16x4 __attribute__((ext_vector_type(4)));
typedef float f32x4 __attribute__((ext_vector_type(4)));
typedef short short8 __attribute__((ext_vector_type(8)));

#define S_LEN 4096
#define EMB   2048
#define NH    16
#define NKV   4
#define HD    128
#define WIN   2048

// 1/sqrt(128) * log2(e): softmax runs in exp2 domain (v_exp_f32 is 2^x).
#define SCALE2 0.12751743f
// T13 defer-rescale threshold (exp2 domain): P bounded by 2^8.
#define DTHR   8.0f

// global_load_lds width=16: wave-uniform LDS base + lane*16; per-lane gsrc.
#define GLOAD_LDS16(g, l) __builtin_amdgcn_global_load_lds( \
    (const __attribute__((address_space(1))) void*)(g),     \
    (__attribute__((address_space(3))) void*)(l), 16, 0, 0)

// ---------------------------------------------------------------------------
// f32 -> bf16 streaming convert (8 elems/thread).
// ---------------------------------------------------------------------------
__global__ __launch_bounds__(256)
void cvt_f32_bf16(const float* __restrict__ X, bf16* __restrict__ Y)
{
    long i = ((long)blockIdx.x * 256 + threadIdx.x) * 8;
    f32x4 a = *(const f32x4*)(X + i);
    f32x4 b = *(const f32x4*)(X + i + 4);
    short8 v;
    #pragma unroll
    for (int k = 0; k < 4; k++) {
        ((bf16*)&v)[k]     = (bf16)a[k];
        ((bf16*)&v)[4 + k] = (bf16)b[k];
    }
    *(short8*)(Y + i) = v;
}

// ---------------------------------------------------------------------------
// Weight transpose+convert: W[K][N] f32 -> Wt[N][K] bf16. 32x32 LDS tiles.
// ---------------------------------------------------------------------------
__global__ __launch_bounds__(256)
void transpose_w(const float* __restrict__ W, bf16* __restrict__ Wt, int K, int N)
{
    __shared__ float t[32][33];
    const int k0 = blockIdx.x * 32, n0 = blockIdx.y * 32;
    const int tx = threadIdx.x & 31, ty = threadIdx.x >> 5;  // ty 0..7
    #pragma unroll
    for (int i = 0; i < 4; i++)
        t[ty + 8 * i][tx] = W[(long)(k0 + ty + 8 * i) * N + n0 + tx];
    __syncthreads();
    #pragma unroll
    for (int i = 0; i < 4; i++)
        Wt[(long)(n0 + ty + 8 * i) * K + k0 + tx] = (bf16)t[tx][ty + 8 * i];
}

// ---------------------------------------------------------------------------
// m97-style MFMA GEMM (bf16 A and Bt): C[M,N] = A * Bt^T, f32 accumulate.
// 128x128 tile, BK=32, 256 thr = 4 waves, wave = 64x64 output.
// Staging: global_load_lds width=16 into LINEAR LDS [row][32] (64B rows).
// No LDS swizzle: at 2-barrier structure the stage+drain dominates and
// ds_read conflicts are hidden [m230/m252 regime gate]; m97 measured 874 TF.
//   lane l of wave w, instr i covers LDS bytes i*4096 + w*1024 + l*16
//   -> row = i*64 + w*16 + (l>>2), kcol = (l&3)*8  (matches gsrc below)
// ---------------------------------------------------------------------------
template<bool C_BF16>
__global__ __launch_bounds__(256)
void gemm_lds(const bf16* __restrict__ A, const bf16* __restrict__ Bt,
              void* __restrict__ Cp, int M, int N, int K)
{
    __shared__ __align__(16) bf16 As[128 * 32];   // [m][k] linear
    __shared__ __align__(16) bf16 Bs[128 * 32];   // [n][k] linear
    char* AsB = (char*)As;
    char* BsB = (char*)Bs;
    const int tid  = threadIdx.x;
    const int n0 = blockIdx.x * 128, m0 = blockIdx.y * 128;
    const int w = tid >> 6;
    const int lane = tid & 63;
    const int wm = (w >> 1) * 64, wn = (w & 1) * 64;
    const int l16 = tid & 15, lq4 = lane >> 4;

    const f32x4 fz = {0.f, 0.f, 0.f, 0.f};
    f32x4 acc[4][4];
    #pragma unroll
    for (int i = 0; i < 4; i++)
        #pragma unroll
        for (int j = 0; j < 4; j++) acc[i][j] = fz;

    // per-lane global sources for the staging DMA
    const int srow = w * 16 + (lane >> 2);      // 0..63 (i adds 64)
    const int scol = (lane & 3) * 8;
    const bf16* Ag = A  + (long)(m0 + srow) * K + scol;
    const bf16* Bg = Bt + (long)(n0 + srow) * K + scol;
    char* Al = AsB + w * 1024 + (lane & 63) * 0;   // wave-uniform base
    char* Bl = BsB + w * 1024;

    for (int k0 = 0; k0 < K; k0 += 32) {
        __syncthreads();   // previous tile's frag reads done
        GLOAD_LDS16(Ag,            Al);
        GLOAD_LDS16(Ag + 64 * K,   Al + 4096);
        GLOAD_LDS16(Bg,            Bl);
        GLOAD_LDS16(Bg + 64 * K,   Bl + 4096);
        __syncthreads();   // compiler drains vmcnt(0) before barrier
        Ag += 32; Bg += 32;

        short8 af[4], bfr[4];
        #pragma unroll
        for (int i = 0; i < 4; i++) {
            af[i]  = *(const short8*)(AsB + (wm + i * 16 + l16) * 64 + lq4 * 16);
            bfr[i] = *(const short8*)(BsB + (wn + i * 16 + l16) * 64 + lq4 * 16);
        }
        #pragma unroll
        for (int i = 0; i < 4; i++)
            #pragma unroll
            for (int j = 0; j < 4; j++)
                acc[i][j] = __builtin_amdgcn_mfma_f32_16x16x32_bf16(
                    af[i], bfr[j], acc[i][j], 0, 0, 0);
    }

    #pragma unroll
    for (int i = 0; i < 4; i++)
        #pragma unroll
        for (int r = 0; r < 4; r++) {
            long row = m0 + wm + i * 16 + lq4 * 4 + r;
            #pragma unroll
            for (int j = 0; j < 4; j++) {
                long col = n0 + wn + j * 16 + l16;
                if (C_BF16) ((bf16*)Cp)[row * N + col] = (bf16)acc[i][j][r];
                else        ((float*)Cp)[row * N + col] = acc[i][j][r];
            }
        }
}

// ---------------------------------------------------------------------------
// MFMA bf16 GEMM, reg-staged with f32->bf16 convert (for f32 A inputs).
// 128x128 tile, BK=32. (unchanged from round 3 — verified passing)
// ---------------------------------------------------------------------------
template<bool A_BF16, bool C_BF16>
__global__ __launch_bounds__(256)
void gemm_mfma(const void* __restrict__ Ap, const bf16* __restrict__ Bt,
               void* __restrict__ Cp, int M, int N, int K)
{
    __shared__ __align__(16) bf16 As[128 * 32];   // [m][k]
    __shared__ __align__(16) bf16 Bs[128 * 32];   // [n][k]
    char* AsB = (char*)As;
    char* BsB = (char*)Bs;
    const int tid = threadIdx.x;
    const int n0 = blockIdx.x * 128, m0 = blockIdx.y * 128;
    const int w = tid >> 6;
    const int wm = (w >> 1) * 64, wn = (w & 1) * 64;
    const int l16 = tid & 15, lq4 = (tid & 63) >> 4;

    const f32x4 fz = {0.f, 0.f, 0.f, 0.f};
    f32x4 acc[4][4];
    #pragma unroll
    for (int i = 0; i < 4; i++)
        #pragma unroll
        for (int j = 0; j < 4; j++) acc[i][j] = fz;

    const int sr = tid >> 1;
    const int sh = (tid & 1) * 16;
    const long arow = (long)(m0 + sr) * K;
    const long brow = (long)(n0 + sr) * K;
    const int wbase = sr * 64;
    const int swz = (sr & 7) << 4;

    for (int k0 = 0; k0 < K; k0 += 32) {
        __syncthreads();
        short8 av0, av1;
        if (A_BF16) {
            const bf16* A = (const bf16*)Ap;
            av0 = *(const short8*)(A + arow + k0 + sh);
            av1 = *(const short8*)(A + arow + k0 + sh + 8);
        } else {
            const float* A = (const float*)Ap;
            f32x4 a0 = *(const f32x4*)(A + arow + k0 + sh);
            f32x4 a1 = *(const f32x4*)(A + arow + k0 + sh + 4);
            f32x4 a2 = *(const f32x4*)(A + arow + k0 + sh + 8);
            f32x4 a3 = *(const f32x4*)(A + arow + k0 + sh + 12);
            bf16* p0 = (bf16*)&av0;
            bf16* p1 = (bf16*)&av1;
            #pragma unroll
            for (int i = 0; i < 4; i++) {
                p0[i]     = (bf16)a0[i];
                p0[4 + i] = (bf16)a1[i];
                p1[i]     = (bf16)a2[i];
                p1[4 + i] = (bf16)a3[i];
            }
        }
        short8 bv0 = *(const short8*)(Bt + brow + k0 + sh);
        short8 bv1 = *(const short8*)(Bt + brow + k0 + sh + 8);
        *(short8*)(AsB + ((wbase + sh * 2     ) ^ swz)) = av0;
        *(short8*)(AsB + ((wbase + sh * 2 + 16) ^ swz)) = av1;
        *(short8*)(BsB + ((wbase + sh * 2     ) ^ swz)) = bv0;
        *(short8*)(BsB + ((wbase + sh * 2 + 16) ^ swz)) = bv1;
        __syncthreads();

        short8 af[4], bfr[4];
        #pragma unroll
        for (int i = 0; i < 4; i++) {
            int mr = wm + i * 16 + l16;
            af[i]  = *(const short8*)(AsB + ((mr * 64 + lq4 * 16) ^ ((mr & 7) << 4)));
            int nr = wn + i * 16 + l16;
            bfr[i] = *(const short8*)(BsB + ((nr * 64 + lq4 * 16) ^ ((nr & 7) << 4)));
        }
        #pragma unroll
        for (int i = 0; i < 4; i++)
            #pragma unroll
            for (int j = 0; j < 4; j++)
                acc[i][j] = __builtin_amdgcn_mfma_f32_16x16x32_bf16(
                    af[i], bfr[j], acc[i][j], 0, 0, 0);
    }

    #pragma unroll
    for (int i = 0; i < 4; i++)
        #pragma unroll
        for (int r = 0; r < 4; r++) {
            long row = m0 + wm + i * 16 + lq4 * 4 + r;
            #pragma unroll
            for (int j = 0; j < 4; j++) {
                long col = n0 + wn + j * 16 + l16;
                if (C_BF16) ((bf16*)Cp)[row * N + col] = (bf16)acc[i][j][r];
                else        ((float*)Cp)[row * N + col] = acc[i][j][r];
            }
        }
}

// ---------------------------------------------------------------------------
// In-place RoPE on bf16 [S][nh*128] (f32 math). position_ids == arange(S).
// ---------------------------------------------------------------------------
__global__ __launch_bounds__(256)
void rope_k(bf16* __restrict__ X, int nh)
{
    int idx = blockIdx.x * 256 + threadIdx.x;
    int i = idx & 63;
    int h = (idx >> 6) % nh;
    int s = idx / (64 * nh);
    bf16* p = X + (long)s * (nh * HD) + h * HD + i;
    float x1 = (float)p[0];
    float x2 = (float)p[64];
    float f = exp2f((float)i * (-13.287712379549449f / 64.0f)); // 10000^(-i/64)
    float ang = (float)s * f;
    float sn, cs;
    sincosf(ang, &sn, &cs);
    p[0]  = (bf16)(x1 * cs - x2 * sn);
    p[64] = (bf16)(x2 * cs + x1 * sn);
}

// ---------------------------------------------------------------------------
// Transpose V: Vb[S][NKV*HD] -> Vt[NKV*HD][S] (row index = kvh*128 + d).
// ---------------------------------------------------------------------------
__global__ __launch_bounds__(256)
void transpose_v(const bf16* __restrict__ V, bf16* __restrict__ Vt)
{
    __shared__ bf16 t[32][33];
    const int s0 = blockIdx.x * 32;
    const int d0 = blockIdx.y * 32;
    const int tx = threadIdx.x & 31, ty = threadIdx.x >> 5; // ty 0..7
    #pragma unroll
    for (int k = 0; k < 4; k++)
        t[ty + 8 * k][tx] = V[(long)(s0 + ty + 8 * k) * (NKV * HD) + d0 + tx];
    __syncthreads();
    #pragma unroll
    for (int k = 0; k < 4; k++) {
        int drow = d0 + ty + 8 * k;
        Vt[(long)drow * S_LEN + s0 + tx] = t[tx][ty + 8 * k];
    }
}

// ---------------------------------------------------------------------------
// MFMA flash attention v4 (sliding-window causal, GQA).
// v3 structure (swapped-operand softmax; 112 VGPR proven) + VALU diet:
//  - softmax in exp2 domain (SCALE2 folds 1/sqrt(128)*log2e; v_exp_f32 = 2^x)
//  - T13 defer-rescale THR=8: skip max-update/alpha/accO-rescale when
//    __all(tmax - mrow <= 8); P bounded by 2^8; num/denom use same rounded P
//  - prefetch addressing by pointer increment (K: +64*512, Vt: +64)
// ---------------------------------------------------------------------------
__global__ __launch_bounds__(256)
void attn_mfma(const bf16* __restrict__ Qb, const bf16* __restrict__ Kb,
               const bf16* __restrict__ Vt, bf16* __restrict__ Ob)
{
    __shared__ __align__(16) bf16 Kl[64 * 128];   // [key][d], byte^=((key&7)<<4)
    __shared__ __align__(16) bf16 Vl[128 * 64];   // [d][key], byte^=((d&7)<<4)
    __shared__ __align__(16) bf16 Pl[4][16][72];  // per-wave P[q][key], pad 72

    const int qb  = (int)gridDim.x - 1 - blockIdx.x;   // LPT: long blocks first
    const int q0  = qb * 64;
    const int h   = blockIdx.y;
    const int kvh = h >> 2;
    const int tid = threadIdx.x;
    const int w   = tid >> 6;
    const int l16 = tid & 15;
    const int lq4 = (tid & 63) >> 4;
    const int qw  = q0 + w * 16;
    const int qi  = qw + l16;            // this lane's softmax q-row

    // Q as B-frag: lane holds Q[qi][c*32 + lq4*8 .. +8]
    short8 aQ[4];
    {
        const bf16* qp = Qb + (long)qi * EMB + h * HD + lq4 * 8;
        #pragma unroll
        for (int c = 0; c < 4; c++) aQ[c] = *(const short8*)(qp + c * 32);
    }

    const f32x4 fz = {0.f, 0.f, 0.f, 0.f};
    float mrow = -1e30f, lrow = 0.f;
    f32x4 accO[8];   // accO[dt][r] = O[qi][dt*16 + lq4*4 + r]
    #pragma unroll
    for (int dt = 0; dt < 8; dt++) accO[dt] = fz;

    const int jb0 = (q0 >= WIN) ? q0 - WIN : 0;
    char* KlB = (char*)Kl;
    char* VlB = (char*)Vl;

    // T14 prefetch pointers (advance by constant stride per tile)
    const bf16* pK = Kb + (long)(jb0 + (tid >> 4)) * (NKV * HD) + kvh * HD + (tid & 15) * 8;
    const bf16* pV = Vt + ((long)kvh * HD + (tid >> 3)) * S_LEN + jb0 + (tid & 7) * 8;

    // prologue: first tile's loads into registers
    short8 stgK[4], stgV[4];
    #pragma unroll
    for (int it = 0; it < 4; it++) {
        stgK[it] = *(const short8*)(pK + it * 16 * (NKV * HD));
        stgV[it] = *(const short8*)(pV + it * 32 * S_LEN);
    }
    pK += 64 * (NKV * HD);
    pV += 64;

    for (int jb = jb0; jb <= q0; jb += 64) {
        __syncthreads();   // previous tile's LDS readers done
        #pragma unroll
        for (int it = 0; it < 4; it++) {
            int c = it * 256 + tid;
            int key = c >> 4, d0 = (c & 15) * 8;
            *(short8*)(KlB + ((key * 256 + d0 * 2) ^ ((key & 7) << 4))) = stgK[it];
            int d = c >> 3, k0 = (c & 7) * 8;
            *(short8*)(VlB + ((d * 128 + k0 * 2) ^ ((d & 7) << 4))) = stgV[it];
        }
        __syncthreads();
        // prefetch next tile (in flight under this tile's compute)
        if (jb + 64 <= q0) {
            #pragma unroll
            for (int it = 0; it < 4; it++) {
                stgK[it] = *(const short8*)(pK + it * 16 * (NKV * HD));
                stgV[it] = *(const short8*)(pV + it * 32 * S_LEN);
            }
            pK += 64 * (NKV * HD);
            pV += 64;
        }

        // --- QK^T swapped: s[jt][r] = S[key = jb+jt*16+lq4*4+r][qi] ---
        f32x4 s[4];
        #pragma unroll
        for (int jt = 0; jt < 4; jt++) {
            const int key = jt * 16 + l16;
            f32x4 a = fz;
            #pragma unroll
            for (int c = 0; c < 4; c++) {
                short8 bk = *(const short8*)(
                    KlB + ((key * 256 + c * 64 + lq4 * 16) ^ ((key & 7) << 4)));
                a = __builtin_amdgcn_mfma_f32_16x16x32_bf16(bk, aQ[c], a, 0, 0, 0);
            }
            s[jt] = a;
        }

        // --- scale to exp2 domain (+mask first/last tile) + per-lane max ---
        float tmax = -1e30f;
        const bool need_mask = (jb == q0) || (q0 >= WIN && jb == jb0);
        if (need_mask) {
            #pragma unroll
            for (int jt = 0; jt < 4; jt++)
                #pragma unroll
                for (int r = 0; r < 4; r++) {
                    int j = jb + jt * 16 + lq4 * 4 + r;
                    float sv = s[jt][r] * SCALE2;
                    if (j > qi || j < qi - WIN) sv = -1e30f;
                    s[jt][r] = sv;
                    tmax = fmaxf(tmax, sv);
                }
        } else {
            #pragma unroll
            for (int jt = 0; jt < 4; jt++)
                #pragma unroll
                for (int r = 0; r < 4; r++) {
                    float sv = s[jt][r] * SCALE2;
                    s[jt][r] = sv;
                    tmax = fmaxf(tmax, sv);
                }
        }
        tmax = fmaxf(tmax, __shfl_xor(tmax, 16, 64));
        tmax = fmaxf(tmax, __shfl_xor(tmax, 32, 64));

        // --- T13: rescale only if some row's max grew past THR ---
        if (!__all(tmax - mrow <= DTHR)) {
            float mn = fmaxf(mrow, tmax);
            float alpha = exp2f(mrow - mn);   // first tile: exp2(-huge)=0
            mrow = mn;
            lrow *= alpha;
            #pragma unroll
            for (int dt = 0; dt < 8; dt++)
                accO[dt] *= alpha;
        }

        // --- P = 2^(s - mrow) (bounded by 2^THR), write P^T tile ---
        float rsum = 0.f;
        #pragma unroll
        for (int jt = 0; jt < 4; jt++) {
            bf16x4 pb4;
            #pragma unroll
            for (int r = 0; r < 4; r++) {
                float pv = exp2f(s[jt][r] - mrow);   // masked -> 0
                bf16 pb = (bf16)pv;
                pb4[r] = pb;
                rsum += (float)pb;   // denom from ROUNDED p (consistency)
            }
            *(bf16x4*)&Pl[w][l16][jt * 16 + lq4 * 4] = pb4;   // 8B write
        }
        rsum += __shfl_xor(rsum, 16, 64);
        rsum += __shfl_xor(rsum, 32, 64);
        lrow += rsum;

        // --- PV swapped: O^T = V^T * P^T ---
        #pragma unroll
        for (int kc = 0; kc < 2; kc++) {
            short8 ap = *(const short8*)&Pl[w][l16][kc * 32 + lq4 * 8];
            #pragma unroll
            for (int dt = 0; dt < 8; dt++) {
                int d = dt * 16 + l16;
                short8 bv = *(const short8*)(
                    VlB + ((d * 128 + kc * 64 + lq4 * 16) ^ ((d & 7) << 4)));
                accO[dt] = __builtin_amdgcn_mfma_f32_16x16x32_bf16(bv, ap, accO[dt], 0, 0, 0);
            }
        }
    }

    // --- epilogue: normalize, pack 4 bf16, one 8B store per dt ---
    float inv = 1.0f / lrow;
    bf16* op = Ob + (long)qi * EMB + h * HD + lq4 * 4;
    #pragma unroll
    for (int dt = 0; dt < 8; dt++) {
        bf16x4 o4;
        #pragma unroll
        for (int r = 0; r < 4; r++) o4[r] = (bf16)(accO[dt][r] * inv);
        *(bf16x4*)(op + dt * 16) = o4;
    }
}

// ---------------------------------------------------------------------------
extern "C" void kernel_launch(void* const* d_in, const int* in_sizes, int n_in,
                              void* d_out, int out_size, void* d_ws, size_t ws_size,
                              hipStream_t stream)
{
    (void)out_size; (void)ws_size;
    int idx_pos = -1;
    for (int i = 0; i < n_in; i++)
        if (in_sizes[i] == 4096) { idx_pos = i; break; }
    int bigs[3] = {0, 1, 2}, w4[2] = {4, 6}, w1[2] = {5, 5};
    int nb = 0, n4 = 0, n1 = 0;
    for (int i = 0; i < n_in; i++) {
        if (in_sizes[i] == 8388608 && nb < 3) bigs[nb++] = i;
        else if (in_sizes[i] == 4194304 && n4 < 2) w4[n4++] = i;
        else if (in_sizes[i] == 1048576 && n1 < 2) w1[n1++] = i;
    }
    bool alpha = (idx_pos == 1);
    int iq  = alpha ? bigs[1] : bigs[0];
    int ik  = alpha ? bigs[0] : bigs[1];
    int iv  = bigs[2];
    int iwq = alpha ? w4[1] : w4[0];
    int iwo = alpha ? w4[0] : w4[1];
    int iwk = w1[0];
    int iwv = w1[1];
    const float* query = (const float*)d_in[iq];
    const float* key   = (const float*)d_in[ik];
    const float* value = (const float*)d_in[iv];
    const float* wq = (const float*)d_in[iwq];
    const float* wk = (const float*)d_in[iwk];
    const float* wv = (const float*)d_in[iwv];
    const float* wo = (const float*)d_in[iwo];

    // Workspace lifetimes (peak 28 MiB, stream-ordered):
    //   phase 1: wqT [0,8M) ; Qf [8,24M)         (gemm-Q reads both)
    //   phase 2: Kb [0,4M), Vb [4,8M)            (overwrite dead wqT)
    //            wkT [24,26M), wvT [26,28M)      (dead before Vt)
    //   phase 3: Vt [24,28M)                     (after wkT/wvT dead)
    //            Ob [8,24M)                      (overwrites dead Qf)
    //   phase 4: woT [0,8M)                      (after attn: Kb/Vb dead)
    bf16* Qb  = (bf16*)d_out;                // d_out[0:16M), dead before final GEMM
    char* ws = (char*)d_ws;
    bf16* wqT = (bf16*)(ws);
    bf16* Qf  = (bf16*)(ws + (8u  << 20));
    bf16* Kb  = (bf16*)(ws);
    bf16* Vb  = (bf16*)(ws + (4u  << 20));
    bf16* Ob  = (bf16*)(ws + (8u  << 20));
    bf16* Vt  = (bf16*)(ws + (24u << 20));
    bf16* wkT = (bf16*)(ws + (24u << 20));
    bf16* wvT = (bf16*)(ws + (26u << 20));
    bf16* woT = (bf16*)(ws);

    dim3 blk(256);
    // phase 1: Q projection (gemm_lds: global_load_lds staging)
    transpose_w<<<dim3(EMB / 32, EMB / 32), blk, 0, stream>>>(wq, wqT, EMB, EMB);
    cvt_f32_bf16<<<(S_LEN * EMB) / 2048, blk, 0, stream>>>(query, Qf);
    gemm_lds<true><<<dim3(EMB / 128, S_LEN / 128), blk, 0, stream>>>(
        Qf, wqT, Qb, S_LEN, EMB, EMB);

    // phase 2: K/V projections (f32 A path, reg-staged)
    transpose_w<<<dim3(EMB / 32, (NKV * HD) / 32), blk, 0, stream>>>(wk, wkT, EMB, NKV * HD);
    transpose_w<<<dim3(EMB / 32, (NKV * HD) / 32), blk, 0, stream>>>(wv, wvT, EMB, NKV * HD);
    gemm_mfma<false, true><<<dim3((NKV * HD) / 128, S_LEN / 128), blk, 0, stream>>>(
        key, wkT, Kb, S_LEN, NKV * HD, EMB);
    gemm_mfma<false, true><<<dim3((NKV * HD) / 128, S_LEN / 128), blk, 0, stream>>>(
        value, wvT, Vb, S_LEN, NKV * HD, EMB);

    // phase 3: RoPE + attention
    rope_k<<<(S_LEN * NH * 64) / 256, blk, 0, stream>>>(Qb, NH);
    rope_k<<<(S_LEN * NKV * 64) / 256, blk, 0, stream>>>(Kb, NKV);
    transpose_v<<<dim3(S_LEN / 32, (NKV * HD) / 32), blk, 0, stream>>>(Vb, Vt);
    attn_mfma<<<dim3(S_LEN / 64, NH), blk, 0, stream>>>(Qb, Kb, Vt, Ob);

    // phase 4: output projection (gemm_lds)
    transpose_w<<<dim3((NH * HD) / 32, EMB / 32), blk, 0, stream>>>(wo, woT, NH * HD, EMB);
    gemm_lds<false><<<dim3(EMB / 128, S_LEN / 128), blk, 0, stream>>>(
        Ob, woT, d_out, S_LEN, EMB, EMB);
}

// Round 8
// 520.129 us; speedup vs baseline: 1.5209x; 1.1799x over previous
//
#include <hip/hip_runtime.h>
#include <hip/hip_bf16.h>
#include <cmath>

typedef __bf16 bf16;
typedef bf16 bf16x4 __attribute__((ext_vector_type(4)));
typedef float f32x4 __attribute__((ext_vector_type(4)));
typedef short short8 __attribute__((ext_vector_type(8)));

#define S_LEN 4096
#define EMB   2048
#define NH    16
#define NKV   4
#define HD    128
#define WIN   2048

// global_load_lds width=16: wave-uniform LDS base + lane*16; per-lane gsrc.
#define GLOAD_LDS16(g, l) __builtin_amdgcn_global_load_lds( \
    (const __attribute__((address_space(1))) void*)(g),     \
    (__attribute__((address_space(3))) void*)(l), 16, 0, 0)

// ---------------------------------------------------------------------------
// f32 -> bf16 streaming convert (8 elems/thread).
// ---------------------------------------------------------------------------
__global__ __launch_bounds__(256)
void cvt_f32_bf16(const float* __restrict__ X, bf16* __restrict__ Y)
{
    long i = ((long)blockIdx.x * 256 + threadIdx.x) * 8;
    f32x4 a = *(const f32x4*)(X + i);
    f32x4 b = *(const f32x4*)(X + i + 4);
    short8 v;
    #pragma unroll
    for (int k = 0; k < 4; k++) {
        ((bf16*)&v)[k]     = (bf16)a[k];
        ((bf16*)&v)[4 + k] = (bf16)b[k];
    }
    *(short8*)(Y + i) = v;
}

// ---------------------------------------------------------------------------
// Weight transpose+convert: W[K][N] f32 -> Wt[N][K] bf16. 32x32 LDS tiles.
// ---------------------------------------------------------------------------
__global__ __launch_bounds__(256)
void transpose_w(const float* __restrict__ W, bf16* __restrict__ Wt, int K, int N)
{
    __shared__ float t[32][33];
    const int k0 = blockIdx.x * 32, n0 = blockIdx.y * 32;
    const int tx = threadIdx.x & 31, ty = threadIdx.x >> 5;  // ty 0..7
    #pragma unroll
    for (int i = 0; i < 4; i++)
        t[ty + 8 * i][tx] = W[(long)(k0 + ty + 8 * i) * N + n0 + tx];
    __syncthreads();
    #pragma unroll
    for (int i = 0; i < 4; i++)
        Wt[(long)(n0 + ty + 8 * i) * K + k0 + tx] = (bf16)t[tx][ty + 8 * i];
}

// Fused wk+wv transpose: blockIdx.z selects tensor (same K, N for both).
__global__ __launch_bounds__(256)
void transpose_w2(const float* __restrict__ W0, const float* __restrict__ W1,
                  bf16* __restrict__ T0, bf16* __restrict__ T1, int K, int N)
{
    const float* W = blockIdx.z ? W1 : W0;
    bf16* Wt = blockIdx.z ? T1 : T0;
    __shared__ float t[32][33];
    const int k0 = blockIdx.x * 32, n0 = blockIdx.y * 32;
    const int tx = threadIdx.x & 31, ty = threadIdx.x >> 5;
    #pragma unroll
    for (int i = 0; i < 4; i++)
        t[ty + 8 * i][tx] = W[(long)(k0 + ty + 8 * i) * N + n0 + tx];
    __syncthreads();
    #pragma unroll
    for (int i = 0; i < 4; i++)
        Wt[(long)(n0 + ty + 8 * i) * K + k0 + tx] = (bf16)t[tx][ty + 8 * i];
}

// ---------------------------------------------------------------------------
// m97-style MFMA GEMM (bf16 A and Bt): C[M,N] = A * Bt^T, f32 accumulate.
// 128x128 tile, BK=32, 256 thr = 4 waves, wave = 64x64 output.
// Staging via global_load_lds width=16 into LINEAR LDS (verified round 6).
// ---------------------------------------------------------------------------
template<bool C_BF16>
__global__ __launch_bounds__(256)
void gemm_lds(const bf16* __restrict__ A, const bf16* __restrict__ Bt,
              void* __restrict__ Cp, int M, int N, int K)
{
    __shared__ __align__(16) bf16 As[128 * 32];   // [m][k] linear
    __shared__ __align__(16) bf16 Bs[128 * 32];   // [n][k] linear
    char* AsB = (char*)As;
    char* BsB = (char*)Bs;
    const int tid  = threadIdx.x;
    const int n0 = blockIdx.x * 128, m0 = blockIdx.y * 128;
    const int w = tid >> 6;
    const int lane = tid & 63;
    const int wm = (w >> 1) * 64, wn = (w & 1) * 64;
    const int l16 = tid & 15, lq4 = lane >> 4;

    const f32x4 fz = {0.f, 0.f, 0.f, 0.f};
    f32x4 acc[4][4];
    #pragma unroll
    for (int i = 0; i < 4; i++)
        #pragma unroll
        for (int j = 0; j < 4; j++) acc[i][j] = fz;

    const int srow = w * 16 + (lane >> 2);
    const int scol = (lane & 3) * 8;
    const bf16* Ag = A  + (long)(m0 + srow) * K + scol;
    const bf16* Bg = Bt + (long)(n0 + srow) * K + scol;
    char* Al = AsB + w * 1024;   // wave-uniform base (+ lane*16 by HW)
    char* Bl = BsB + w * 1024;

    for (int k0 = 0; k0 < K; k0 += 32) {
        __syncthreads();
        GLOAD_LDS16(Ag,          Al);
        GLOAD_LDS16(Ag + 64 * K, Al + 4096);
        GLOAD_LDS16(Bg,          Bl);
        GLOAD_LDS16(Bg + 64 * K, Bl + 4096);
        __syncthreads();
        Ag += 32; Bg += 32;

        short8 af[4], bfr[4];
        #pragma unroll
        for (int i = 0; i < 4; i++) {
            af[i]  = *(const short8*)(AsB + (wm + i * 16 + l16) * 64 + lq4 * 16);
            bfr[i] = *(const short8*)(BsB + (wn + i * 16 + l16) * 64 + lq4 * 16);
        }
        #pragma unroll
        for (int i = 0; i < 4; i++)
            #pragma unroll
            for (int j = 0; j < 4; j++)
                acc[i][j] = __builtin_amdgcn_mfma_f32_16x16x32_bf16(
                    af[i], bfr[j], acc[i][j], 0, 0, 0);
    }

    #pragma unroll
    for (int i = 0; i < 4; i++)
        #pragma unroll
        for (int r = 0; r < 4; r++) {
            long row = m0 + wm + i * 16 + lq4 * 4 + r;
            #pragma unroll
            for (int j = 0; j < 4; j++) {
                long col = n0 + wn + j * 16 + l16;
                if (C_BF16) ((bf16*)Cp)[row * N + col] = (bf16)acc[i][j][r];
                else        ((float*)Cp)[row * N + col] = acc[i][j][r];
            }
        }
}

// ---------------------------------------------------------------------------
// Fused K+V projection GEMM (f32 A, reg-staged; proven round-3 body).
// blockIdx.z selects (key,wkT,Kb) vs (value,wvT,Vb). Grid 4x32x2 = 256
// blocks -> all CUs busy (each separate GEMM alone fills only half).
// ---------------------------------------------------------------------------
__global__ __launch_bounds__(256)
void gemm_kv(const float* __restrict__ Ka, const float* __restrict__ Va,
             const bf16* __restrict__ KBt, const bf16* __restrict__ VBt,
             bf16* __restrict__ KC, bf16* __restrict__ VC,
             int M, int N, int K)
{
    const float* Ap = blockIdx.z ? Va : Ka;
    const bf16*  Bt = blockIdx.z ? VBt : KBt;
    bf16*        Cp = blockIdx.z ? VC : KC;

    __shared__ __align__(16) bf16 As[128 * 32];   // [m][k]
    __shared__ __align__(16) bf16 Bs[128 * 32];   // [n][k]
    char* AsB = (char*)As;
    char* BsB = (char*)Bs;
    const int tid = threadIdx.x;
    const int n0 = blockIdx.x * 128, m0 = blockIdx.y * 128;
    const int w = tid >> 6;
    const int wm = (w >> 1) * 64, wn = (w & 1) * 64;
    const int l16 = tid & 15, lq4 = (tid & 63) >> 4;

    const f32x4 fz = {0.f, 0.f, 0.f, 0.f};
    f32x4 acc[4][4];
    #pragma unroll
    for (int i = 0; i < 4; i++)
        #pragma unroll
        for (int j = 0; j < 4; j++) acc[i][j] = fz;

    const int sr = tid >> 1;
    const int sh = (tid & 1) * 16;
    const long arow = (long)(m0 + sr) * K;
    const long brow = (long)(n0 + sr) * K;
    const int wbase = sr * 64;
    const int swz = (sr & 7) << 4;

    for (int k0 = 0; k0 < K; k0 += 32) {
        __syncthreads();
        short8 av0, av1;
        {
            const float* A = Ap;
            f32x4 a0 = *(const f32x4*)(A + arow + k0 + sh);
            f32x4 a1 = *(const f32x4*)(A + arow + k0 + sh + 4);
            f32x4 a2 = *(const f32x4*)(A + arow + k0 + sh + 8);
            f32x4 a3 = *(const f32x4*)(A + arow + k0 + sh + 12);
            bf16* p0 = (bf16*)&av0;
            bf16* p1 = (bf16*)&av1;
            #pragma unroll
            for (int i = 0; i < 4; i++) {
                p0[i]     = (bf16)a0[i];
                p0[4 + i] = (bf16)a1[i];
                p1[i]     = (bf16)a2[i];
                p1[4 + i] = (bf16)a3[i];
            }
        }
        short8 bv0 = *(const short8*)(Bt + brow + k0 + sh);
        short8 bv1 = *(const short8*)(Bt + brow + k0 + sh + 8);
        *(short8*)(AsB + ((wbase + sh * 2     ) ^ swz)) = av0;
        *(short8*)(AsB + ((wbase + sh * 2 + 16) ^ swz)) = av1;
        *(short8*)(BsB + ((wbase + sh * 2     ) ^ swz)) = bv0;
        *(short8*)(BsB + ((wbase + sh * 2 + 16) ^ swz)) = bv1;
        __syncthreads();

        short8 af[4], bfr[4];
        #pragma unroll
        for (int i = 0; i < 4; i++) {
            int mr = wm + i * 16 + l16;
            af[i]  = *(const short8*)(AsB + ((mr * 64 + lq4 * 16) ^ ((mr & 7) << 4)));
            int nr = wn + i * 16 + l16;
            bfr[i] = *(const short8*)(BsB + ((nr * 64 + lq4 * 16) ^ ((nr & 7) << 4)));
        }
        #pragma unroll
        for (int i = 0; i < 4; i++)
            #pragma unroll
            for (int j = 0; j < 4; j++)
                acc[i][j] = __builtin_amdgcn_mfma_f32_16x16x32_bf16(
                    af[i], bfr[j], acc[i][j], 0, 0, 0);
    }

    #pragma unroll
    for (int i = 0; i < 4; i++)
        #pragma unroll
        for (int r = 0; r < 4; r++) {
            long row = m0 + wm + i * 16 + lq4 * 4 + r;
            #pragma unroll
            for (int j = 0; j < 4; j++) {
                long col = n0 + wn + j * 16 + l16;
                Cp[row * N + col] = (bf16)acc[i][j][r];
            }
        }
}

// ---------------------------------------------------------------------------
// In-place RoPE on bf16 [S][nh*128] (f32 math). position_ids == arange(S).
// ---------------------------------------------------------------------------
__global__ __launch_bounds__(256)
void rope_k(bf16* __restrict__ X, int nh)
{
    int idx = blockIdx.x * 256 + threadIdx.x;
    int i = idx & 63;
    int h = (idx >> 6) % nh;
    int s = idx / (64 * nh);
    bf16* p = X + (long)s * (nh * HD) + h * HD + i;
    float x1 = (float)p[0];
    float x2 = (float)p[64];
    float f = exp2f((float)i * (-13.287712379549449f / 64.0f)); // 10000^(-i/64)
    float ang = (float)s * f;
    float sn, cs;
    sincosf(ang, &sn, &cs);
    p[0]  = (bf16)(x1 * cs - x2 * sn);
    p[64] = (bf16)(x2 * cs + x1 * sn);
}

// ---------------------------------------------------------------------------
// Transpose V: Vb[S][NKV*HD] -> Vt[NKV*HD][S] (row index = kvh*128 + d).
// ---------------------------------------------------------------------------
__global__ __launch_bounds__(256)
void transpose_v(const bf16* __restrict__ V, bf16* __restrict__ Vt)
{
    __shared__ bf16 t[32][33];
    const int s0 = blockIdx.x * 32;
    const int d0 = blockIdx.y * 32;
    const int tx = threadIdx.x & 31, ty = threadIdx.x >> 5; // ty 0..7
    #pragma unroll
    for (int k = 0; k < 4; k++)
        t[ty + 8 * k][tx] = V[(long)(s0 + ty + 8 * k) * (NKV * HD) + d0 + tx];
    __syncthreads();
    #pragma unroll
    for (int k = 0; k < 4; k++) {
        int drow = d0 + ty + 8 * k;
        Vt[(long)drow * S_LEN + s0 + tx] = t[tx][ty + 8 * k];
    }
}

// ---------------------------------------------------------------------------
// MFMA flash attention (round-5 proven source, 153 us) + ONE change:
// Pl pad-72 -> [16][64] with XOR swizzle byte^=((l16&7)<<4) on BOTH write
// and read (bijective per row; 2-way bank alias only = free).
// LDS total 16K+16K+8K = 40960 B -> 4 blocks/CU fit exactly (4x40960=160Ki).
// ---------------------------------------------------------------------------
__global__ __launch_bounds__(256)
void attn_mfma(const bf16* __restrict__ Qb, const bf16* __restrict__ Kb,
               const bf16* __restrict__ Vt, bf16* __restrict__ Ob)
{
    __shared__ __align__(16) bf16 Kl[64 * 128];   // [key][d], byte^=((key&7)<<4)
    __shared__ __align__(16) bf16 Vl[128 * 64];   // [d][key], byte^=((d&7)<<4)
    __shared__ __align__(16) bf16 Pl[4][16][64];  // per-wave P[q][key], XOR swz

    const int qb  = (int)gridDim.x - 1 - blockIdx.x;   // LPT: long blocks first
    const int q0  = qb * 64;
    const int h   = blockIdx.y;
    const int kvh = h >> 2;
    const int tid = threadIdx.x;
    const int w   = tid >> 6;
    const int l16 = tid & 15;
    const int lq4 = (tid & 63) >> 4;
    const int qw  = q0 + w * 16;
    const int qi  = qw + l16;            // this lane's softmax q-row

    // Q as B-frag: lane holds Q[qi][c*32 + lq4*8 .. +8]
    short8 aQ[4];
    {
        const bf16* qp = Qb + (long)qi * EMB + h * HD + lq4 * 8;
        #pragma unroll
        for (int c = 0; c < 4; c++) aQ[c] = *(const short8*)(qp + c * 32);
    }

    const f32x4 fz = {0.f, 0.f, 0.f, 0.f};
    float mrow = -1e30f, lrow = 0.f;
    f32x4 accO[8];   // accO[dt][r] = O[qi][dt*16 + lq4*4 + r]
    #pragma unroll
    for (int dt = 0; dt < 8; dt++) accO[dt] = fz;

    const int jb0 = (q0 >= WIN) ? q0 - WIN : 0;
    char* KlB = (char*)Kl;
    char* VlB = (char*)Vl;
    char* PlB = (char*)Pl + w * 2048;   // this wave's P tile

    // T14 prologue: first tile's loads into registers
    short8 stgK[4], stgV[4];
    #pragma unroll
    for (int it = 0; it < 4; it++) {
        int c = it * 256 + tid;
        stgK[it] = *(const short8*)(Kb + (long)(jb0 + (c >> 4)) * (NKV * HD) + kvh * HD + (c & 15) * 8);
        stgV[it] = *(const short8*)(Vt + ((long)kvh * HD + (c >> 3)) * S_LEN + jb0 + (c & 7) * 8);
    }

    for (int jb = jb0; jb <= q0; jb += 64) {
        __syncthreads();   // previous tile's LDS readers done
        #pragma unroll
        for (int it = 0; it < 4; it++) {
            int c = it * 256 + tid;
            int key = c >> 4, d0 = (c & 15) * 8;
            *(short8*)(KlB + ((key * 256 + d0 * 2) ^ ((key & 7) << 4))) = stgK[it];
            int d = c >> 3, k0 = (c & 7) * 8;
            *(short8*)(VlB + ((d * 128 + k0 * 2) ^ ((d & 7) << 4))) = stgV[it];
        }
        __syncthreads();
        // prefetch next tile (in flight under this tile's compute)
        if (jb + 64 <= q0) {
            #pragma unroll
            for (int it = 0; it < 4; it++) {
                int c = it * 256 + tid;
                stgK[it] = *(const short8*)(Kb + (long)(jb + 64 + (c >> 4)) * (NKV * HD) + kvh * HD + (c & 15) * 8);
                stgV[it] = *(const short8*)(Vt + ((long)kvh * HD + (c >> 3)) * S_LEN + jb + 64 + (c & 7) * 8);
            }
        }

        // --- QK^T swapped: s[jt][r] = S[key = jb+jt*16+lq4*4+r][qi] ---
        f32x4 s[4];
        #pragma unroll
        for (int jt = 0; jt < 4; jt++) {
            const int key = jt * 16 + l16;
            f32x4 a = fz;
            #pragma unroll
            for (int c = 0; c < 4; c++) {
                short8 bk = *(const short8*)(
                    KlB + ((key * 256 + c * 64 + lq4 * 16) ^ ((key & 7) << 4)));
                a = __builtin_amdgcn_mfma_f32_16x16x32_bf16(bk, aQ[c], a, 0, 0, 0);
            }
            s[jt] = a;
        }

        // --- scale (+mask only first/last tile) + per-lane row max ---
        float tmax = -1e30f;
        const bool need_mask = (jb == q0) || (q0 >= WIN && jb == jb0);
        if (need_mask) {
            #pragma unroll
            for (int jt = 0; jt < 4; jt++)
                #pragma unroll
                for (int r = 0; r < 4; r++) {
                    int j = jb + jt * 16 + lq4 * 4 + r;
                    float sv = s[jt][r] * 0.08838834764831845f;  // 1/sqrt(128)
                    if (j > qi || j < qi - WIN) sv = -1e30f;
                    s[jt][r] = sv;
                    tmax = fmaxf(tmax, sv);
                }
        } else {
            #pragma unroll
            for (int jt = 0; jt < 4; jt++)
                #pragma unroll
                for (int r = 0; r < 4; r++) {
                    float sv = s[jt][r] * 0.08838834764831845f;
                    s[jt][r] = sv;
                    tmax = fmaxf(tmax, sv);
                }
        }
        tmax = fmaxf(tmax, __shfl_xor(tmax, 16, 64));
        tmax = fmaxf(tmax, __shfl_xor(tmax, 32, 64));

        // --- online softmax update (scalars; lane owns row qi) ---
        float mn = fmaxf(mrow, tmax);
        float alpha = __expf(mrow - mn);   // first tile: exp(-huge)=0
        mrow = mn;
        float rsum = 0.f;
        #pragma unroll
        for (int jt = 0; jt < 4; jt++) {
            bf16x4 pb4;
            #pragma unroll
            for (int r = 0; r < 4; r++) {
                float pv = __expf(s[jt][r] - mn);   // masked -> 0
                bf16 pb = (bf16)pv;
                pb4[r] = pb;
                rsum += (float)pb;   // denom from ROUNDED p (consistency)
            }
            // P^T write, XOR-swizzled (8B, alignment preserved: swz bit4)
            *(bf16x4*)(PlB + ((l16 * 128 + jt * 32 + lq4 * 8) ^ ((l16 & 7) << 4))) = pb4;
        }
        rsum += __shfl_xor(rsum, 16, 64);
        rsum += __shfl_xor(rsum, 32, 64);
        lrow = lrow * alpha + rsum;
        #pragma unroll
        for (int dt = 0; dt < 8; dt++)
            accO[dt] *= alpha;

        // --- PV swapped: O^T = V^T * P^T ---
        #pragma unroll
        for (int kc = 0; kc < 2; kc++) {
            short8 ap = *(const short8*)(
                PlB + ((l16 * 128 + kc * 64 + lq4 * 16) ^ ((l16 & 7) << 4)));
            #pragma unroll
            for (int dt = 0; dt < 8; dt++) {
                int d = dt * 16 + l16;
                short8 bv = *(const short8*)(
                    VlB + ((d * 128 + kc * 64 + lq4 * 16) ^ ((d & 7) << 4)));
                accO[dt] = __builtin_amdgcn_mfma_f32_16x16x32_bf16(bv, ap, accO[dt], 0, 0, 0);
            }
        }
    }

    // --- epilogue: normalize, pack 4 bf16, one 8B store per dt ---
    float inv = 1.0f / lrow;
    bf16* op = Ob + (long)qi * EMB + h * HD + lq4 * 4;
    #pragma unroll
    for (int dt = 0; dt < 8; dt++) {
        bf16x4 o4;
        #pragma unroll
        for (int r = 0; r < 4; r++) o4[r] = (bf16)(accO[dt][r] * inv);
        *(bf16x4*)(op + dt * 16) = o4;
    }
}

// ---------------------------------------------------------------------------
extern "C" void kernel_launch(void* const* d_in, const int* in_sizes, int n_in,
                              void* d_out, int out_size, void* d_ws, size_t ws_size,
                              hipStream_t stream)
{
    (void)out_size; (void)ws_size;
    int idx_pos = -1;
    for (int i = 0; i < n_in; i++)
        if (in_sizes[i] == 4096) { idx_pos = i; break; }
    int bigs[3] = {0, 1, 2}, w4[2] = {4, 6}, w1[2] = {5, 5};
    int nb = 0, n4 = 0, n1 = 0;
    for (int i = 0; i < n_in; i++) {
        if (in_sizes[i] == 8388608 && nb < 3) bigs[nb++] = i;
        else if (in_sizes[i] == 4194304 && n4 < 2) w4[n4++] = i;
        else if (in_sizes[i] == 1048576 && n1 < 2) w1[n1++] = i;
    }
    bool alpha = (idx_pos == 1);
    int iq  = alpha ? bigs[1] : bigs[0];
    int ik  = alpha ? bigs[0] : bigs[1];
    int iv  = bigs[2];
    int iwq = alpha ? w4[1] : w4[0];
    int iwo = alpha ? w4[0] : w4[1];
    int iwk = w1[0];
    int iwv = w1[1];
    const float* query = (const float*)d_in[iq];
    const float* key   = (const float*)d_in[ik];
    const float* value = (const float*)d_in[iv];
    const float* wq = (const float*)d_in[iwq];
    const float* wk = (const float*)d_in[iwk];
    const float* wv = (const float*)d_in[iwv];
    const float* wo = (const float*)d_in[iwo];

    // Workspace lifetimes (peak 28 MiB, stream-ordered):
    //   phase 1: wqT [0,8M) ; Qf [8,24M)         (gemm-Q reads both)
    //   phase 2: Kb [0,4M), Vb [4,8M)            (overwrite dead wqT)
    //            wkT [24,26M), wvT [26,28M)      (dead before Vt)
    //   phase 3: Vt [24,28M)                     (after wkT/wvT dead)
    //            Ob [8,24M)                      (overwrites dead Qf)
    //   phase 4: woT [0,8M)                      (after attn: Kb/Vb dead)
    bf16* Qb  = (bf16*)d_out;                // d_out[0:16M), dead before final GEMM
    char* ws = (char*)d_ws;
    bf16* wqT = (bf16*)(ws);
    bf16* Qf  = (bf16*)(ws + (8u  << 20));
    bf16* Kb  = (bf16*)(ws);
    bf16* Vb  = (bf16*)(ws + (4u  << 20));
    bf16* Ob  = (bf16*)(ws + (8u  << 20));
    bf16* Vt  = (bf16*)(ws + (24u << 20));
    bf16* wkT = (bf16*)(ws + (24u << 20));
    bf16* wvT = (bf16*)(ws + (26u << 20));
    bf16* woT = (bf16*)(ws);

    dim3 blk(256);
    // phase 1: Q projection (gemm_lds: global_load_lds staging)
    transpose_w<<<dim3(EMB / 32, EMB / 32), blk, 0, stream>>>(wq, wqT, EMB, EMB);
    cvt_f32_bf16<<<(S_LEN * EMB) / 2048, blk, 0, stream>>>(query, Qf);
    gemm_lds<true><<<dim3(EMB / 128, S_LEN / 128), blk, 0, stream>>>(
        Qf, wqT, Qb, S_LEN, EMB, EMB);

    // phase 2: K/V projections fused (256 blocks -> full chip)
    transpose_w2<<<dim3(EMB / 32, (NKV * HD) / 32, 2), blk, 0, stream>>>(
        wk, wv, wkT, wvT, EMB, NKV * HD);
    gemm_kv<<<dim3((NKV * HD) / 128, S_LEN / 128, 2), blk, 0, stream>>>(
        key, value, wkT, wvT, Kb, Vb, S_LEN, NKV * HD, EMB);

    // phase 3: RoPE + attention
    rope_k<<<(S_LEN * NH * 64) / 256, blk, 0, stream>>>(Qb, NH);
    rope_k<<<(S_LEN * NKV * 64) / 256, blk, 0, stream>>>(Kb, NKV);
    transpose_v<<<dim3(S_LEN / 32, (NKV * HD) / 32), blk, 0, stream>>>(Vb, Vt);
    attn_mfma<<<dim3(S_LEN / 64, NH), blk, 0, stream>>>(Qb, Kb, Vt, Ob);

    // phase 4: output projection (gemm_lds)
    transpose_w<<<dim3((NH * HD) / 32, EMB / 32), blk, 0, stream>>>(wo, woT, NH * HD, EMB);
    gemm_lds<false><<<dim3(EMB / 128, S_LEN / 128), blk, 0, stream>>>(
        Ob, woT, d_out, S_LEN, EMB, EMB);
}